// Round 7
// baseline (395.796 us; speedup 1.0000x reference)
//
#include <hip/hip_runtime.h>
#include <math.h>

#define N_ROWS 262144
#define D 256
#define C 1000
#define SLABS 32
#define RPS (N_ROWS / SLABS)     // 8192 rows per slab
#define COLG 8                   // 8 column groups of 32 cols
#define PSTRIDE (C * 32)         // floats per partial block (32000)
#define TILE 32
#define NTILE 32                         // ceil(C/TILE)
#define NPAIR (NTILE * (NTILE + 1) / 2)  // 528 triangular tile pairs

typedef float f4v __attribute__((ext_vector_type(4)));

// ---------------- streaming partial class-sums ----------------
// 256 blocks (1/CU): block b = slab (b>>3) x column-group (b&7).
// 1024 threads: row_off = tid>>5 (0..31), col = tid&31.
// Streams its slab's rows sequentially (coalesced 128B per half-wave),
// scatters into LDS acc[1000][32] via ds-atomics (bank = col, conflict-free).
__global__ __launch_bounds__(1024) void k_partial(
    const float* __restrict__ feat, const int* __restrict__ labels,
    float* __restrict__ partial, unsigned int* __restrict__ minb,
    unsigned int* __restrict__ done) {
    int b = blockIdx.x;
    int s = b >> 3;
    int g = b & 7;
    int tid = threadIdx.x;
    int row_off = tid >> 5;
    int col = tid & 31;

    if (b == 0) {
        if (tid == 0) *minb = 0x7f800000u;  // +inf
        if (tid == 1) *done = 0u;
    }

    __shared__ float acc[C * 32];  // 128 KB
    for (int i = tid; i < C * 32; i += 1024) acc[i] = 0.f;
    __syncthreads();

    int base0 = s * RPS + row_off;
    int colbase = g * 32 + col;
    for (int it = 0; it < RPS / 256; ++it) {
        int base = base0 + it * 256;
        int cls[8];
        float v[8];
        #pragma unroll
        for (int u = 0; u < 8; ++u) {
            int r = base + u * 32;
            cls[u] = labels[r];                       // broadcast across 32 lanes
            v[u] = feat[(size_t)r * D + colbase];     // 128B coalesced per half-wave
        }
        #pragma unroll
        for (int u = 0; u < 8; ++u)
            atomicAdd(&acc[cls[u] * 32 + col], v[u]); // LDS atomic, bank=col
    }
    __syncthreads();

    // write partial block (coalesced float4)
    f4v* p4 = reinterpret_cast<f4v*>(partial + (size_t)b * PSTRIDE);
    const f4v* a4 = reinterpret_cast<const f4v*>(acc);
    for (int i = tid; i < PSTRIDE / 4; i += 1024) p4[i] = a4[i];
}

// ---------------- reduce partials -> L2-normalize (counts cancel!) ----------------
// mn = sums / ||sums||  ==  (sums/n) / ||sums/n||
__global__ __launch_bounds__(256) void k_norm(
    const float* __restrict__ partial, float* __restrict__ mn) {
    int c = blockIdx.x;
    int d = threadIdx.x;      // 0..255
    int g = d >> 5, cl = d & 31;

    float sum = 0.f;
    #pragma unroll 4
    for (int s = 0; s < SLABS; ++s)
        sum += partial[(size_t)(s * COLG + g) * PSTRIDE + c * 32 + cl];

    float ss = sum * sum;
    #pragma unroll
    for (int o = 32; o; o >>= 1) ss += __shfl_down(ss, o, 64);
    __shared__ float w[4];
    if ((d & 63) == 0) w[d >> 6] = ss;
    __syncthreads();
    float tot = w[0] + w[1] + w[2] + w[3];
    mn[(size_t)c * D + d] = sum * rsqrtf(tot);
}

// ---------------- min off-diagonal cosine distance (triangular tiles, fused final) ----
__global__ __launch_bounds__(256) void k_mindist(
    const float* __restrict__ mn, unsigned int* __restrict__ minb,
    unsigned int* __restrict__ done, float* __restrict__ out) {
    int t = blockIdx.x;
    int bi = 0;
    while (t >= NTILE - bi) { t -= NTILE - bi; ++bi; }
    int bj = bi + t;
    int i0 = bi * TILE, j0 = bj * TILE;

    __shared__ float A[TILE * D];
    __shared__ float B[TILE * D];
    float4* A4 = reinterpret_cast<float4*>(A);
    float4* B4 = reinterpret_cast<float4*>(B);
    int tid = threadIdx.x;

    for (int k = tid; k < TILE * (D / 4); k += 256) {
        int r = k >> 6;       // row in tile
        int g = k & 63;       // float4 group
        int sg = g ^ ((r >> 1) & 7);
        int gi = i0 + r, gj = j0 + r;
        float4 z = make_float4(0.f, 0.f, 0.f, 0.f);
        A4[r * 64 + sg] = (gi < C) ? reinterpret_cast<const float4*>(mn + (size_t)gi * D)[g] : z;
        B4[r * 64 + sg] = (gj < C) ? reinterpret_cast<const float4*>(mn + (size_t)gj * D)[g] : z;
    }
    __syncthreads();

    int ti = tid >> 4, tj = tid & 15;
    int il = ti * 2, jl = tj * 2;
    int sa = ti & 7;
    int sb = tj & 7;

    float a00 = 0.f, a01 = 0.f, a10 = 0.f, a11 = 0.f;
    #pragma unroll 4
    for (int g = 0; g < 64; ++g) {
        float4 x0 = A4[il * 64 + (g ^ sa)];
        float4 x1 = A4[(il + 1) * 64 + (g ^ sa)];
        float4 y0 = B4[jl * 64 + (g ^ sb)];
        float4 y1 = B4[(jl + 1) * 64 + (g ^ sb)];
        a00 += x0.x * y0.x + x0.y * y0.y + x0.z * y0.z + x0.w * y0.w;
        a01 += x0.x * y1.x + x0.y * y1.y + x0.z * y1.z + x0.w * y1.w;
        a10 += x1.x * y0.x + x1.y * y0.y + x1.z * y0.z + x1.w * y0.w;
        a11 += x1.x * y1.x + x1.y * y1.y + x1.z * y1.z + x1.w * y1.w;
    }

    float m = INFINITY;
    int gi0 = i0 + il, gj0 = j0 + jl;
    if (gi0 < C && gj0 < C && gi0 != gj0)         m = fminf(m, 1.f - fminf(fmaxf(a00, -1.f), 1.f));
    if (gi0 < C && gj0 + 1 < C && gi0 != gj0 + 1) m = fminf(m, 1.f - fminf(fmaxf(a01, -1.f), 1.f));
    if (gi0 + 1 < C && gj0 < C && gi0 + 1 != gj0) m = fminf(m, 1.f - fminf(fmaxf(a10, -1.f), 1.f));
    if (gi0 + 1 < C && gj0 + 1 < C && gi0 != gj0) m = fminf(m, 1.f - fminf(fmaxf(a11, -1.f), 1.f));

    #pragma unroll
    for (int o = 32; o; o >>= 1) m = fminf(m, __shfl_down(m, o, 64));
    if ((tid & 63) == 0) atomicMin(minb, __float_as_uint(m));

    __syncthreads();
    if (tid == 0) {
        __threadfence();
        unsigned int old = atomicAdd(done, 1u);
        if (old == (unsigned int)(gridDim.x - 1)) {
            float d = __uint_as_float(atomicOr(minb, 0u));
            out[0] = logf(1.0f / (d + 1e-6f) + 1.0f);
        }
    }
}

extern "C" void kernel_launch(void* const* d_in, const int* in_sizes, int n_in,
                              void* d_out, int out_size, void* d_ws, size_t ws_size,
                              hipStream_t stream) {
    const float* feat   = (const float*)d_in[0];
    const int*   labels = (const int*)d_in[1];
    float* out = (float*)d_out;

    float*    partial = (float*)d_ws;                        // [256 * 32000]
    float*    mnrm    = partial + (size_t)SLABS * COLG * PSTRIDE;  // [C*D]
    unsigned* minb    = (unsigned*)(mnrm + (size_t)C * D);   // [1]
    unsigned* done    = minb + 1;                            // [1]

    k_partial<<<SLABS * COLG, 1024, 0, stream>>>(feat, labels, partial, minb, done);
    k_norm<<<C, 256, 0, stream>>>(partial, mnrm);
    k_mindist<<<NPAIR, 256, 0, stream>>>(mnrm, minb, done, out);
}

// Round 8
// 153.814 us; speedup vs baseline: 2.5732x; 2.5732x over previous
//
#include <hip/hip_runtime.h>
#include <math.h>

#define N_ROWS 262144
#define D 256
#define C 1000
#define CAP 512                          // per-class list capacity (E[n]=262)
#define TILE 32
#define NTILE 32                         // ceil(C/TILE)
#define NPAIR (NTILE * (NTILE + 1) / 2)  // 528 triangular tile pairs
#define NWV 8                            // waves per centroid block
#define SLOTS 16                         // LDS ring slots per wave (1 KB each)
#define DEPTH 8                          // rows in flight per wave

typedef float f4v __attribute__((ext_vector_type(4)));

// ---------------- init: zero counters, min = +inf, done = 0 ----------------
__global__ void k_init(int* __restrict__ cnt, unsigned int* __restrict__ minb,
                       unsigned int* __restrict__ done) {
    int t = threadIdx.x;
    cnt[t] = 0;  // 1024 threads cover C=1000
    if (t == 0) *minb = 0x7f800000u;
    if (t == 1) *done = 0u;
}

// ---------------- build per-class row lists (one pass, global atomics) ----------------
__global__ void k_build(const int4* __restrict__ lab4, int* __restrict__ cnt,
                        int* __restrict__ list) {
    int i = blockIdx.x * 256 + threadIdx.x;  // 0..65535
    int4 l = lab4[i];
    int base = i * 4;
    list[l.x * CAP + atomicAdd(&cnt[l.x], 1)] = base;
    list[l.y * CAP + atomicAdd(&cnt[l.y], 1)] = base + 1;
    list[l.z * CAP + atomicAdd(&cnt[l.z], 1)] = base + 2;
    list[l.w * CAP + atomicAdd(&cnt[l.w], 1)] = base + 3;
}

// ---------------- per-class gather via global_load_lds ring -> sum -> normalize --------
// 1 block (512 thr = 8 waves) per class. Each wave stages whole 1 KB rows directly
// to LDS with global_load_lds (8 rows in flight, counted vmcnt), then ds_read+add.
__global__ __launch_bounds__(512) void k_centroid(
    const float* __restrict__ feat, const int* __restrict__ list,
    const int* __restrict__ cnt, float* __restrict__ mn) {
    int c = blockIdx.x;
    int tid = threadIdx.x;
    int w = tid >> 6;      // wave 0..7
    int lane = tid & 63;
    int n = cnt[c];
    int nl = (n < CAP) ? n : CAP;

    __shared__ __align__(16) char stage[NWV * SLOTS * 1024];  // 128 KB
    __shared__ int srow[CAP];                                 // 2 KB
    __shared__ f4v part[NWV][64];                             // 8 KB

    for (int i = tid; i < nl; i += 512) srow[i] = list[c * CAP + i];
    __syncthreads();

    // wave w owns list entries w, w+8, w+16, ...
    int nw = (nl > w) ? ((nl - 1 - w) / NWV + 1) : 0;
    char* wst = stage + (size_t)w * (SLOTS * 1024);

#define ISSUE(I)                                                                     \
    do {                                                                             \
        int row_ = srow[w + (I)*NWV];                                                \
        const float* gs_ = feat + (size_t)row_ * D + lane * 4;                       \
        char* ds_ = wst + ((I) & (SLOTS - 1)) * 1024;                                \
        __builtin_amdgcn_global_load_lds(                                            \
            (const __attribute__((address_space(1))) void*)gs_,                      \
            (__attribute__((address_space(3))) void*)ds_, 16, 0, 0);                 \
    } while (0)

    f4v acc = {0.f, 0.f, 0.f, 0.f};
    int nfly = (nw < DEPTH) ? nw : DEPTH;
    for (int s = 0; s < nfly; ++s) ISSUE(s);
    int steady = nw - nfly;
    for (int i = 0; i < steady; ++i) {
        asm volatile("s_waitcnt vmcnt(7)" ::: "memory");   // oldest row landed
        __builtin_amdgcn_sched_barrier(0);
        acc += *(const f4v*)(wst + (i & (SLOTS - 1)) * 1024 + lane * 16);
        ISSUE(i + DEPTH);                                  // refill a DIFFERENT slot
    }
    asm volatile("s_waitcnt vmcnt(0)" ::: "memory");
    __builtin_amdgcn_sched_barrier(0);
    for (int i = steady; i < nw; ++i)
        acc += *(const f4v*)(wst + (i & (SLOTS - 1)) * 1024 + lane * 16);
#undef ISSUE

    // cross-wave reduce + L2-normalize (count divide cancels under normalization)
    part[w][lane] = acc;
    __syncthreads();
    if (w == 0) {
        f4v t = {0.f, 0.f, 0.f, 0.f};
        #pragma unroll
        for (int i = 0; i < NWV; ++i) t += part[i][lane];
        float ss = t.x * t.x + t.y * t.y + t.z * t.z + t.w * t.w;
        #pragma unroll
        for (int o = 32; o; o >>= 1) ss += __shfl_down(ss, o, 64);
        ss = __shfl(ss, 0, 64);
        float rn = rsqrtf(ss);
        f4v o4 = t * rn;
        reinterpret_cast<f4v*>(mn + (size_t)c * D)[lane] = o4;
    }
}

// ---------------- min off-diagonal cosine distance (triangular tiles, fused final) ----
__global__ __launch_bounds__(256) void k_mindist(
    const float* __restrict__ mn, unsigned int* __restrict__ minb,
    unsigned int* __restrict__ done, float* __restrict__ out) {
    int t = blockIdx.x;
    int bi = 0;
    while (t >= NTILE - bi) { t -= NTILE - bi; ++bi; }
    int bj = bi + t;
    int i0 = bi * TILE, j0 = bj * TILE;

    __shared__ float A[TILE * D];
    __shared__ float B[TILE * D];
    float4* A4 = reinterpret_cast<float4*>(A);
    float4* B4 = reinterpret_cast<float4*>(B);
    int tid = threadIdx.x;

    for (int k = tid; k < TILE * (D / 4); k += 256) {
        int r = k >> 6;       // row in tile
        int g = k & 63;       // float4 group
        int sg = g ^ ((r >> 1) & 7);
        int gi = i0 + r, gj = j0 + r;
        float4 z = make_float4(0.f, 0.f, 0.f, 0.f);
        A4[r * 64 + sg] = (gi < C) ? reinterpret_cast<const float4*>(mn + (size_t)gi * D)[g] : z;
        B4[r * 64 + sg] = (gj < C) ? reinterpret_cast<const float4*>(mn + (size_t)gj * D)[g] : z;
    }
    __syncthreads();

    int ti = tid >> 4, tj = tid & 15;
    int il = ti * 2, jl = tj * 2;
    int sa = ti & 7;
    int sb = tj & 7;

    float a00 = 0.f, a01 = 0.f, a10 = 0.f, a11 = 0.f;
    #pragma unroll 4
    for (int g = 0; g < 64; ++g) {
        float4 x0 = A4[il * 64 + (g ^ sa)];
        float4 x1 = A4[(il + 1) * 64 + (g ^ sa)];
        float4 y0 = B4[jl * 64 + (g ^ sb)];
        float4 y1 = B4[(jl + 1) * 64 + (g ^ sb)];
        a00 += x0.x * y0.x + x0.y * y0.y + x0.z * y0.z + x0.w * y0.w;
        a01 += x0.x * y1.x + x0.y * y1.y + x0.z * y1.z + x0.w * y1.w;
        a10 += x1.x * y0.x + x1.y * y0.y + x1.z * y0.z + x1.w * y0.w;
        a11 += x1.x * y1.x + x1.y * y1.y + x1.z * y1.z + x1.w * y1.w;
    }

    float m = INFINITY;
    int gi0 = i0 + il, gj0 = j0 + jl;
    if (gi0 < C && gj0 < C && gi0 != gj0)         m = fminf(m, 1.f - fminf(fmaxf(a00, -1.f), 1.f));
    if (gi0 < C && gj0 + 1 < C && gi0 != gj0 + 1) m = fminf(m, 1.f - fminf(fmaxf(a01, -1.f), 1.f));
    if (gi0 + 1 < C && gj0 < C && gi0 + 1 != gj0) m = fminf(m, 1.f - fminf(fmaxf(a10, -1.f), 1.f));
    if (gi0 + 1 < C && gj0 + 1 < C && gi0 != gj0) m = fminf(m, 1.f - fminf(fmaxf(a11, -1.f), 1.f));

    #pragma unroll
    for (int o = 32; o; o >>= 1) m = fminf(m, __shfl_down(m, o, 64));
    if ((tid & 63) == 0) atomicMin(minb, __float_as_uint(m));

    __syncthreads();
    if (tid == 0) {
        __threadfence();
        unsigned int old = atomicAdd(done, 1u);
        if (old == (unsigned int)(gridDim.x - 1)) {
            float d = __uint_as_float(atomicOr(minb, 0u));
            out[0] = logf(1.0f / (d + 1e-6f) + 1.0f);
        }
    }
}

extern "C" void kernel_launch(void* const* d_in, const int* in_sizes, int n_in,
                              void* d_out, int out_size, void* d_ws, size_t ws_size,
                              hipStream_t stream) {
    const float* feat   = (const float*)d_in[0];
    const int*   labels = (const int*)d_in[1];
    float* out = (float*)d_out;

    int*      cnt  = (int*)d_ws;                 // [1024]
    int*      list = cnt + 1024;                 // [C*CAP]
    float*    mnrm = (float*)(list + C * CAP);   // [C*D]
    unsigned* minb = (unsigned*)(mnrm + C * D);  // [1]
    unsigned* done = minb + 1;                   // [1]

    k_init<<<1, 1024, 0, stream>>>(cnt, minb, done);
    k_build<<<N_ROWS / 4 / 256, 256, 0, stream>>>((const int4*)labels, cnt, list);
    k_centroid<<<C, 512, 0, stream>>>(feat, list, cnt, mnrm);
    k_mindist<<<NPAIR, 256, 0, stream>>>(mnrm, minb, done, out);
}

// Round 9
// 125.222 us; speedup vs baseline: 3.1608x; 1.2283x over previous
//
#include <hip/hip_runtime.h>
#include <math.h>

#define N_ROWS 262144
#define D 256
#define C 1000
#define TILE 32
#define NTILE 32                         // ceil(C/TILE)
#define NPAIR (NTILE * (NTILE + 1) / 2)  // 528 triangular tile pairs

#define NCHUNK 8
#define CHUNK_I4 (N_ROWS / 4 / NCHUNK)   // 8192 int4 per chunk
#define IPT (CHUNK_I4 / 512)             // 16 int4 loads per thread per chunk
#define LCAP 96                          // per-chunk row-list capacity (E=32.8, +11 sigma)

typedef float f4v __attribute__((ext_vector_type(4)));

// ---------------- fused: label scan -> windowed row gather -> L2-normalize ----------------
// 1 block (512 thr = 8 waves) per class. Scans all labels from L2 (same 1 MB for
// every block), in NCHUNK row-windows; the scan of chunk k+1 overlaps the HBM/L3
// gather of chunk k. All blocks walk windows in rough lockstep -> clustered gather
// footprint (~32 MB), the structure that measured fastest (r5).
__global__ __launch_bounds__(512) void k_centroid(
    const float* __restrict__ feat, const int4* __restrict__ lab4,
    float* __restrict__ mn, unsigned int* __restrict__ minb,
    unsigned int* __restrict__ done) {
    int c = blockIdx.x;
    int tid = threadIdx.x;
    int w = tid >> 6;    // wave 0..7
    int cg_ = tid & 63;  // float4 column group

    if (c == 0) {
        if (tid == 0) *minb = 0x7f800000u;
        if (tid == 1) *done = 0u;
    }

    __shared__ int list[NCHUNK][LCAP];
    __shared__ int nlist[NCHUNK];
    if (tid < NCHUNK) nlist[tid] = 0;
    __syncthreads();

    // scan chunk 0
    {
        #pragma unroll 8
        for (int i = 0; i < IPT; ++i) {
            int idx = i * 512 + tid;
            int4 v = lab4[idx];
            int row = idx * 4;
            if (v.x == c) { int p = atomicAdd(&nlist[0], 1); if (p < LCAP) list[0][p] = row; }
            if (v.y == c) { int p = atomicAdd(&nlist[0], 1); if (p < LCAP) list[0][p] = row + 1; }
            if (v.z == c) { int p = atomicAdd(&nlist[0], 1); if (p < LCAP) list[0][p] = row + 2; }
            if (v.w == c) { int p = atomicAdd(&nlist[0], 1); if (p < LCAP) list[0][p] = row + 3; }
        }
    }
    __syncthreads();

    f4v acc = {0.f, 0.f, 0.f, 0.f};
    for (int k = 0; k < NCHUNK; ++k) {
        // scan next chunk (different list buffer; overlaps this chunk's gather)
        if (k + 1 < NCHUNK) {
            int base = (k + 1) * CHUNK_I4;
            int kk = k + 1;
            #pragma unroll 8
            for (int i = 0; i < IPT; ++i) {
                int idx = base + i * 512 + tid;
                int4 v = lab4[idx];
                int row = idx * 4;
                if (v.x == c) { int p = atomicAdd(&nlist[kk], 1); if (p < LCAP) list[kk][p] = row; }
                if (v.y == c) { int p = atomicAdd(&nlist[kk], 1); if (p < LCAP) list[kk][p] = row + 1; }
                if (v.z == c) { int p = atomicAdd(&nlist[kk], 1); if (p < LCAP) list[kk][p] = row + 2; }
                if (v.w == c) { int p = atomicAdd(&nlist[kk], 1); if (p < LCAP) list[kk][p] = row + 3; }
            }
        }
        // gather chunk k's rows (count finalized before the preceding barrier)
        int nl = nlist[k];
        nl = (nl < LCAP) ? nl : LCAP;
        int r = w;
        for (; r + 24 < nl; r += 32) {
            int r0 = list[k][r];
            int r1 = list[k][r + 8];
            int r2 = list[k][r + 16];
            int r3 = list[k][r + 24];
            f4v v0 = reinterpret_cast<const f4v*>(feat + (size_t)r0 * D)[cg_];
            f4v v1 = reinterpret_cast<const f4v*>(feat + (size_t)r1 * D)[cg_];
            f4v v2 = reinterpret_cast<const f4v*>(feat + (size_t)r2 * D)[cg_];
            f4v v3 = reinterpret_cast<const f4v*>(feat + (size_t)r3 * D)[cg_];
            acc += v0 + v1 + v2 + v3;
        }
        for (; r < nl; r += 8) {
            int row = list[k][r];
            acc += reinterpret_cast<const f4v*>(feat + (size_t)row * D)[cg_];
        }
        __syncthreads();
    }

    // cross-wave reduce + L2-normalize (count divide cancels under normalization)
    __shared__ f4v part[8][64];
    part[w][cg_] = acc;
    __syncthreads();
    if (w == 0) {
        f4v t = {0.f, 0.f, 0.f, 0.f};
        #pragma unroll
        for (int i = 0; i < 8; ++i) t += part[i][cg_];
        float ss = t.x * t.x + t.y * t.y + t.z * t.z + t.w * t.w;
        #pragma unroll
        for (int o = 32; o; o >>= 1) ss += __shfl_down(ss, o, 64);
        ss = __shfl(ss, 0, 64);
        float rn = rsqrtf(ss);
        f4v o4 = t * rn;
        reinterpret_cast<f4v*>(mn + (size_t)c * D)[cg_] = o4;
    }
}

// ---------------- min off-diagonal cosine distance (triangular tiles, fused final) ----
__global__ __launch_bounds__(256) void k_mindist(
    const float* __restrict__ mn, unsigned int* __restrict__ minb,
    unsigned int* __restrict__ done, float* __restrict__ out) {
    int t = blockIdx.x;
    int bi = 0;
    while (t >= NTILE - bi) { t -= NTILE - bi; ++bi; }
    int bj = bi + t;
    int i0 = bi * TILE, j0 = bj * TILE;

    __shared__ float A[TILE * D];
    __shared__ float B[TILE * D];
    float4* A4 = reinterpret_cast<float4*>(A);
    float4* B4 = reinterpret_cast<float4*>(B);
    int tid = threadIdx.x;

    for (int k = tid; k < TILE * (D / 4); k += 256) {
        int r = k >> 6;       // row in tile
        int g = k & 63;       // float4 group
        int sg = g ^ ((r >> 1) & 7);
        int gi = i0 + r, gj = j0 + r;
        float4 z = make_float4(0.f, 0.f, 0.f, 0.f);
        A4[r * 64 + sg] = (gi < C) ? reinterpret_cast<const float4*>(mn + (size_t)gi * D)[g] : z;
        B4[r * 64 + sg] = (gj < C) ? reinterpret_cast<const float4*>(mn + (size_t)gj * D)[g] : z;
    }
    __syncthreads();

    int ti = tid >> 4, tj = tid & 15;
    int il = ti * 2, jl = tj * 2;
    int sa = ti & 7;
    int sb = tj & 7;

    float a00 = 0.f, a01 = 0.f, a10 = 0.f, a11 = 0.f;
    #pragma unroll 4
    for (int g = 0; g < 64; ++g) {
        float4 x0 = A4[il * 64 + (g ^ sa)];
        float4 x1 = A4[(il + 1) * 64 + (g ^ sa)];
        float4 y0 = B4[jl * 64 + (g ^ sb)];
        float4 y1 = B4[(jl + 1) * 64 + (g ^ sb)];
        a00 += x0.x * y0.x + x0.y * y0.y + x0.z * y0.z + x0.w * y0.w;
        a01 += x0.x * y1.x + x0.y * y1.y + x0.z * y1.z + x0.w * y1.w;
        a10 += x1.x * y0.x + x1.y * y0.y + x1.z * y0.z + x1.w * y0.w;
        a11 += x1.x * y1.x + x1.y * y1.y + x1.z * y1.z + x1.w * y1.w;
    }

    float m = INFINITY;
    int gi0 = i0 + il, gj0 = j0 + jl;
    if (gi0 < C && gj0 < C && gi0 != gj0)         m = fminf(m, 1.f - fminf(fmaxf(a00, -1.f), 1.f));
    if (gi0 < C && gj0 + 1 < C && gi0 != gj0 + 1) m = fminf(m, 1.f - fminf(fmaxf(a01, -1.f), 1.f));
    if (gi0 + 1 < C && gj0 < C && gi0 + 1 != gj0) m = fminf(m, 1.f - fminf(fmaxf(a10, -1.f), 1.f));
    if (gi0 + 1 < C && gj0 + 1 < C && gi0 != gj0) m = fminf(m, 1.f - fminf(fmaxf(a11, -1.f), 1.f));

    #pragma unroll
    for (int o = 32; o; o >>= 1) m = fminf(m, __shfl_down(m, o, 64));
    if ((tid & 63) == 0) atomicMin(minb, __float_as_uint(m));

    __syncthreads();
    if (tid == 0) {
        __threadfence();
        unsigned int old = atomicAdd(done, 1u);
        if (old == (unsigned int)(gridDim.x - 1)) {
            float d = __uint_as_float(atomicOr(minb, 0u));
            out[0] = logf(1.0f / (d + 1e-6f) + 1.0f);
        }
    }
}

extern "C" void kernel_launch(void* const* d_in, const int* in_sizes, int n_in,
                              void* d_out, int out_size, void* d_ws, size_t ws_size,
                              hipStream_t stream) {
    const float* feat   = (const float*)d_in[0];
    const int*   labels = (const int*)d_in[1];
    float* out = (float*)d_out;

    float*    mnrm = (float*)d_ws;               // [C*D]
    unsigned* minb = (unsigned*)(mnrm + C * D);  // [1]
    unsigned* done = minb + 1;                   // [1]

    k_centroid<<<C, 512, 0, stream>>>(feat, (const int4*)labels, mnrm, minb, done);
    k_mindist<<<NPAIR, 256, 0, stream>>>(mnrm, minb, done, out);
}